// Round 1
// baseline (2114.867 us; speedup 1.0000x reference)
//
#include <hip/hip_runtime.h>
#include <math.h>

#define B_    32
#define S_    2048
#define C_    1536
#define N_    200
#define KSEL  128

// ---------------- kernel 1: partial sums of x over s (per batch) ----------------
// grid (6 cchunk, 16 schunk, 32 b) x 256
__global__ void ksum_part(const float* __restrict__ x, float* __restrict__ part) {
    int cchunk = blockIdx.x;
    int schunk = blockIdx.y;
    int b      = blockIdx.z;
    int c = cchunk * 256 + threadIdx.x;
    const float* xp = x + ((size_t)(b * S_ + schunk * 128)) * C_ + c;
    float acc = 0.f;
    #pragma unroll 4
    for (int s = 0; s < 128; ++s) acc += xp[(size_t)s * C_];
    part[(size_t)(b * 16 + schunk) * C_ + c] = acc;
}

// ---------------- kernel 2: reduce partials -> sum_x[b][c] ----------------
// grid (6, 32) x 256
__global__ void ksum_reduce(const float* __restrict__ part, float* __restrict__ sumx) {
    int c = blockIdx.x * 256 + threadIdx.x;
    int b = blockIdx.y;
    float acc = 0.f;
    #pragma unroll
    for (int k = 0; k < 16; ++k) acc += part[(size_t)(b * 16 + k) * C_ + c];
    sumx[(size_t)b * C_ + c] = acc;
}

// ---------------- kernel 3: scores = sum_x . W[n] + S*bias[n]; argmax -> max_ids[b] ----
// grid (32) x 256
__global__ void kscore_argmax(const float* __restrict__ sumx, const float* __restrict__ W,
                              const float* __restrict__ bias, int* __restrict__ max_ids) {
    int b = blockIdx.x;
    __shared__ float lx[C_];
    __shared__ float sc[256];
    for (int i = threadIdx.x; i < C_; i += 256) lx[i] = sumx[(size_t)b * C_ + i];
    __syncthreads();
    int n = threadIdx.x;
    float acc = -1e30f;
    if (n < N_) {
        acc = 0.f;
        const float* wr = W + (size_t)n * C_;
        for (int c = 0; c < C_; ++c) acc += lx[c] * wr[c];
        acc += (float)S_ * bias[n];
    }
    sc[threadIdx.x] = acc;
    __syncthreads();
    if (threadIdx.x == 0) {
        int best = 0; float bv = sc[0];
        for (int i = 1; i < N_; ++i) { if (sc[i] > bv) { bv = sc[i]; best = i; } }
        max_ids[b] = best;
    }
}

// ---------------- kernel 4: main GEMM + fused softmax-column epilogue ----------------
// block: 128 tokens x 256 (padded) classes; 512 threads; thread tile 8x8
#define TM  128
#define TNP 256
#define BK  16
#define XP  (TM + 4)    // 132, +4 pad breaks bank alias on transposed stores
#define WP  (TNP + 4)   // 260

__launch_bounds__(512)
__global__ void kgemm_col(const float* __restrict__ x, const float* __restrict__ W,
                          const float* __restrict__ bias, const int* __restrict__ max_ids,
                          float* __restrict__ col) {
    __shared__ float xs[BK * XP];
    __shared__ float wsm[BK * WP];
    const int tid = threadIdx.x;
    const int blk = blockIdx.x;        // 0..511
    const int t0  = blk * TM;
    const int cg  = tid & 31;          // class group 0..31 (8 classes each)
    const int tg  = tid >> 5;          // token group 0..15 (8 tokens each)

    float acc[8][8];
    #pragma unroll
    for (int i = 0; i < 8; ++i)
        #pragma unroll
        for (int j = 0; j < 8; ++j) acc[i][j] = 0.f;

    const int ltok = tid >> 2;         // 0..127
    const int lk4  = (tid & 3) * 4;    // 0,4,8,12
    const float* xbase = x + (size_t)(t0 + ltok) * C_ + lk4;

    for (int kb = 0; kb < C_ / BK; ++kb) {
        const int k0 = kb * BK;
        // stage x tile (transposed: xs[kk][token])
        float4 xv = *(const float4*)(xbase + k0);
        xs[(lk4 + 0) * XP + ltok] = xv.x;
        xs[(lk4 + 1) * XP + ltok] = xv.y;
        xs[(lk4 + 2) * XP + ltok] = xv.z;
        xs[(lk4 + 3) * XP + ltok] = xv.w;
        // stage W tile (transposed: wsm[kk][class]), zero-pad classes >= 200
        #pragma unroll
        for (int r = 0; r < 2; ++r) {
            int n = (tid >> 2) + r * 128;
            float4 wv = make_float4(0.f, 0.f, 0.f, 0.f);
            if (n < N_) wv = *(const float4*)(W + (size_t)n * C_ + k0 + lk4);
            wsm[(lk4 + 0) * WP + n] = wv.x;
            wsm[(lk4 + 1) * WP + n] = wv.y;
            wsm[(lk4 + 2) * WP + n] = wv.z;
            wsm[(lk4 + 3) * WP + n] = wv.w;
        }
        __syncthreads();
        #pragma unroll
        for (int kk = 0; kk < BK; ++kk) {
            float4 xa = *(const float4*)&xs[kk * XP + tg * 8];
            float4 xb = *(const float4*)&xs[kk * XP + tg * 8 + 4];
            float4 wa = *(const float4*)&wsm[kk * WP + cg * 8];
            float4 wb = *(const float4*)&wsm[kk * WP + cg * 8 + 4];
            float xr[8] = {xa.x, xa.y, xa.z, xa.w, xb.x, xb.y, xb.z, xb.w};
            float wr[8] = {wa.x, wa.y, wa.z, wa.w, wb.x, wb.y, wb.z, wb.w};
            #pragma unroll
            for (int i = 0; i < 8; ++i)
                #pragma unroll
                for (int j = 0; j < 8; ++j)
                    acc[i][j] += xr[i] * wr[j];
        }
        __syncthreads();
    }

    // ---- epilogue: per-token softmax prob of class m, reduced across the 32
    //      class-groups that live in one half-wave (lane = (tg&1)*32 + cg) ----
    const int m    = max_ids[t0 / S_];     // block lies fully inside one batch
    const int lane = tid & 63;
    float bb[8];
    #pragma unroll
    for (int j = 0; j < 8; ++j) {
        int n = cg * 8 + j;
        bb[j] = (n < N_) ? bias[n] : 0.f;
    }
    const int cgm = m >> 3, jm = m & 7;
    #pragma unroll
    for (int i = 0; i < 8; ++i) {
        float l[8];
        #pragma unroll
        for (int j = 0; j < 8; ++j) {
            int n = cg * 8 + j;
            l[j] = (n < N_) ? (acc[i][j] + bb[j]) : -1e30f;
        }
        float mx = l[0];
        #pragma unroll
        for (int j = 1; j < 8; ++j) mx = fmaxf(mx, l[j]);
        #pragma unroll
        for (int off = 1; off < 32; off <<= 1) mx = fmaxf(mx, __shfl_xor(mx, off, 64));
        float se = 0.f;
        #pragma unroll
        for (int j = 0; j < 8; ++j) se += expf(l[j] - mx);
        #pragma unroll
        for (int off = 1; off < 32; off <<= 1) se += __shfl_xor(se, off, 64);
        // broadcast logit of class m from the lane holding it (within this half-wave)
        float lc = acc[i][jm] + bb[jm];
        float lm = __shfl(lc, (lane & 32) + cgm, 64);
        if (cg == 0) col[t0 + tg * 8 + i] = expf(lm - mx) / se;
    }
}

// ---------------- kernel 5: exact stable top-k by rank counting ----------------
// grid (8 ichunk, 32 b) x 256; rank(i) = #{j: v[j]>v[i] or (v[j]==v[i] and j<i)}
__global__ void ktopk(const float* __restrict__ col, int* __restrict__ topk) {
    int ichunk = blockIdx.x;
    int b      = blockIdx.y;
    __shared__ float v[S_];
    #pragma unroll
    for (int r = 0; r < 8; ++r)
        v[threadIdx.x + r * 256] = col[(size_t)b * S_ + threadIdx.x + r * 256];
    __syncthreads();
    int i = ichunk * 256 + threadIdx.x;
    float vi = v[i];
    int cnt = 0;
    const float4* v4 = (const float4*)v;
    for (int j4 = 0; j4 < S_ / 4; ++j4) {
        float4 q = v4[j4];
        int j = j4 * 4;
        cnt += (q.x > vi) || (q.x == vi && (j + 0) < i);
        cnt += (q.y > vi) || (q.y == vi && (j + 1) < i);
        cnt += (q.z > vi) || (q.z == vi && (j + 2) < i);
        cnt += (q.w > vi) || (q.w == vi && (j + 3) < i);
    }
    if (cnt < KSEL) topk[b * KSEL + cnt] = i;
}

// ---------------- kernel 6: gather selected rows ----------------
// grid (128 k, 32 b) x 384 (float4 per thread)
__global__ void kgather(const float* __restrict__ x, const int* __restrict__ topk,
                        float* __restrict__ out) {
    int k = blockIdx.x;
    int b = blockIdx.y;
    int t = topk[b * KSEL + k];
    const float4* src = (const float4*)(x + (size_t)(b * S_ + t) * C_);
    float4*       dst = (float4*)(out + (size_t)(b * KSEL + k) * C_);
    dst[threadIdx.x] = src[threadIdx.x];
}

extern "C" void kernel_launch(void* const* d_in, const int* in_sizes, int n_in,
                              void* d_out, int out_size, void* d_ws, size_t ws_size,
                              hipStream_t stream) {
    const float* x    = (const float*)d_in[0];   // [32,2048,1536]
    const float* W    = (const float*)d_in[1];   // [200,1536]
    const float* bias = (const float*)d_in[2];   // [200]
    float* out = (float*)d_out;                  // [32,128,1536]

    // workspace layout (~3.6 MB total)
    float* part = (float*)d_ws;                  // 32*16*1536
    float* sumx = part + 32 * 16 * C_;           // 32*1536
    float* col  = sumx + 32 * C_;                // 65536
    int*   mids = (int*)(col + B_ * S_);         // 32
    int*   topk = mids + 32;                     // 32*128

    ksum_part<<<dim3(6, 16, 32), 256, 0, stream>>>(x, part);
    ksum_reduce<<<dim3(6, 32), 256, 0, stream>>>(part, sumx);
    kscore_argmax<<<32, 256, 0, stream>>>(sumx, W, bias, mids);
    kgemm_col<<<(B_ * S_) / TM, 512, 0, stream>>>(x, W, bias, mids, col);
    ktopk<<<dim3(8, 32), 256, 0, stream>>>(col, topk);
    kgather<<<dim3(KSEL, 32), 384, 0, stream>>>(x, topk, out);
}

// Round 2
// 1208.544 us; speedup vs baseline: 1.7499x; 1.7499x over previous
//
#include <hip/hip_runtime.h>
#include <math.h>

#define B_    32
#define S_    2048
#define C_    1536
#define N_    200
#define KSEL  128

typedef float float2v __attribute__((ext_vector_type(2)));
typedef float float4v __attribute__((ext_vector_type(4)));

// v_pk_fma_f32 with op_sel broadcast of one W scalar from a float2 pair.
// lo: both result halves use w.lo ; hi: both use w.hi. x uses both halves (2 tokens).
#define PK_LO(a, xv, wv) asm("v_pk_fma_f32 %0, %1, %2, %0 op_sel:[0,0,0] op_sel_hi:[1,0,1]" \
                             : "+v"(a) : "v"(xv), "v"(wv))
#define PK_HI(a, xv, wv) asm("v_pk_fma_f32 %0, %1, %2, %0 op_sel:[0,1,0] op_sel_hi:[1,1,1]" \
                             : "+v"(a) : "v"(xv), "v"(wv))

// ---------------- kernel 1: partial sums of x over s (per batch) ----------------
__global__ void ksum_part(const float* __restrict__ x, float* __restrict__ part) {
    int cchunk = blockIdx.x;
    int schunk = blockIdx.y;
    int b      = blockIdx.z;
    int c = cchunk * 256 + threadIdx.x;
    const float* xp = x + ((size_t)(b * S_ + schunk * 128)) * C_ + c;
    float acc = 0.f;
    #pragma unroll 4
    for (int s = 0; s < 128; ++s) acc += xp[(size_t)s * C_];
    part[(size_t)(b * 16 + schunk) * C_ + c] = acc;
}

// ---------------- kernel 2: reduce partials -> sum_x[b][c] ----------------
__global__ void ksum_reduce(const float* __restrict__ part, float* __restrict__ sumx) {
    int c = blockIdx.x * 256 + threadIdx.x;
    int b = blockIdx.y;
    float acc = 0.f;
    #pragma unroll
    for (int k = 0; k < 16; ++k) acc += part[(size_t)(b * 16 + k) * C_ + c];
    sumx[(size_t)b * C_ + c] = acc;
}

// ---------------- kernel 3: scores + argmax, coalesced (wave-per-class) ----------
// grid (32) x 256 (4 waves). scores[n] = sum_x . W[n] + S*b[n]; argmax -> max_ids[b]
__global__ void kscore_argmax(const float* __restrict__ sumx, const float* __restrict__ W,
                              const float* __restrict__ bias, int* __restrict__ max_ids) {
    int b = blockIdx.x;
    __shared__ float lx[C_];
    __shared__ float sc[N_];
    for (int i = threadIdx.x; i < C_; i += 256) lx[i] = sumx[(size_t)b * C_ + i];
    __syncthreads();
    const int wid = threadIdx.x >> 6, lane = threadIdx.x & 63;
    for (int n = wid; n < N_; n += 4) {
        const float* wr = W + (size_t)n * C_;
        float p = 0.f;
        #pragma unroll
        for (int q = 0; q < 6; ++q) {          // 6 * 64 lanes * 4 = 1536
            int c = q * 256 + lane * 4;
            float4 w4 = *(const float4*)(wr + c);
            float4 x4 = *(const float4*)(lx + c);
            p += w4.x * x4.x + w4.y * x4.y + w4.z * x4.z + w4.w * x4.w;
        }
        #pragma unroll
        for (int off = 1; off < 64; off <<= 1) p += __shfl_xor(p, off, 64);
        if (lane == 0) sc[n] = p + (float)S_ * bias[n];
    }
    __syncthreads();
    if (threadIdx.x == 0) {
        int best = 0; float bv = sc[0];
        for (int i = 1; i < N_; ++i) { if (sc[i] > bv) { bv = sc[i]; best = i; } }
        max_ids[b] = best;
    }
}

// ---------------- kernel 4: GEMM + fused softmax-column epilogue ------------------
// 256 threads (4 waves). Block tile: 128 tokens x 256 classes (padded, N=200 real).
// Microtile: 16 tokens x 8 classes per thread; token-pairs in v_pk_fma_f32 halves.
// Lane cg owns classes {cg*4..+3} U {128+cg*4..+3}  -> lane-consecutive b128 W reads
// (conflict-free). x reads are 32-lane broadcasts (free).
#define TM    128
#define XS_LD 132      // 128 + 4 pad (store conflict break)
#define WS_LD 260      // 256 + 4 pad

__launch_bounds__(256, 2)
__global__ void kgemm_col(const float* __restrict__ x, const float* __restrict__ W,
                          const float* __restrict__ bias, const int* __restrict__ max_ids,
                          float* __restrict__ col) {
    __shared__ float xs[16 * XS_LD];    // [kk][token]
    __shared__ float wsm[16 * WS_LD];   // [kk][class]
    const int tid = threadIdx.x;
    const int cg  = tid & 31;           // class group 0..31
    const int tg  = tid >> 5;           // token group 0..7 (16 tokens each)
    const int t0  = blockIdx.x * TM;

    float2v acc[8][8];                  // [token-pair][class]
    #pragma unroll
    for (int i = 0; i < 8; ++i)
        #pragma unroll
        for (int j = 0; j < 8; ++j) acc[i][j] = (float2v){0.f, 0.f};

    const int ltok = tid >> 2;          // 0..63
    const int lk4  = (tid & 3) * 4;     // 0,4,8,12
    const float* xb0 = x + (size_t)(t0 + ltok) * C_ + lk4;
    const float* xb1 = x + (size_t)(t0 + 64 + ltok) * C_ + lk4;

    for (int kb = 0; kb < C_ / 16; ++kb) {
        const int k0 = kb * 16;
        float4 xv0 = *(const float4*)(xb0 + k0);
        float4 xv1 = *(const float4*)(xb1 + k0);
        float4 wv[4];
        #pragma unroll
        for (int r = 0; r < 4; ++r) {
            int n = ltok + r * 64;
            wv[r] = make_float4(0.f, 0.f, 0.f, 0.f);
            if (n < N_) wv[r] = *(const float4*)(W + (size_t)n * C_ + k0 + lk4);
        }
        __syncthreads();   // previous iteration's compute done before overwrite
        xs[(lk4 + 0) * XS_LD + ltok] = xv0.x;
        xs[(lk4 + 1) * XS_LD + ltok] = xv0.y;
        xs[(lk4 + 2) * XS_LD + ltok] = xv0.z;
        xs[(lk4 + 3) * XS_LD + ltok] = xv0.w;
        xs[(lk4 + 0) * XS_LD + 64 + ltok] = xv1.x;
        xs[(lk4 + 1) * XS_LD + 64 + ltok] = xv1.y;
        xs[(lk4 + 2) * XS_LD + 64 + ltok] = xv1.z;
        xs[(lk4 + 3) * XS_LD + 64 + ltok] = xv1.w;
        #pragma unroll
        for (int r = 0; r < 4; ++r) {
            int n = ltok + r * 64;
            wsm[(lk4 + 0) * WS_LD + n] = wv[r].x;
            wsm[(lk4 + 1) * WS_LD + n] = wv[r].y;
            wsm[(lk4 + 2) * WS_LD + n] = wv[r].z;
            wsm[(lk4 + 3) * WS_LD + n] = wv[r].w;
        }
        __syncthreads();
        #pragma unroll
        for (int kk = 0; kk < 16; ++kk) {
            const float4v* xrow = (const float4v*)&xs[kk * XS_LD + tg * 16];
            float4v x0 = xrow[0], x1 = xrow[1], x2_ = xrow[2], x3 = xrow[3];
            float4v wa = *(const float4v*)&wsm[kk * WS_LD + cg * 4];
            float4v wb = *(const float4v*)&wsm[kk * WS_LD + 128 + cg * 4];
            float2v xp[8] = {x0.xy, x0.zw, x1.xy, x1.zw, x2_.xy, x2_.zw, x3.xy, x3.zw};
            float2v wp[4] = {wa.xy, wa.zw, wb.xy, wb.zw};
            #pragma unroll
            for (int i = 0; i < 8; ++i) {
                #pragma unroll
                for (int jp = 0; jp < 4; ++jp) {
                    PK_LO(acc[i][2 * jp + 0], xp[i], wp[jp]);
                    PK_HI(acc[i][2 * jp + 1], xp[i], wp[jp]);
                }
            }
        }
    }

    // ---- epilogue: softmax prob of class m per token; reduce over half-wave ----
    const int m    = max_ids[t0 / S_];
    const int lane = tid & 63;
    float bb[8];
    #pragma unroll
    for (int j = 0; j < 8; ++j) {
        int n = (j < 4) ? (cg * 4 + j) : (128 + cg * 4 + (j - 4));
        bb[j] = (n < N_) ? bias[n] : 0.f;
    }
    int cq, jq;
    if (m < 128) { cq = m >> 2; jq = m & 3; }
    else         { cq = (m - 128) >> 2; jq = 4 + ((m - 128) & 3); }

    #pragma unroll
    for (int i = 0; i < 8; ++i) {
        #pragma unroll
        for (int par = 0; par < 2; ++par) {
            float l[8];
            #pragma unroll
            for (int j = 0; j < 8; ++j) {
                int n = (j < 4) ? (cg * 4 + j) : (128 + cg * 4 + (j - 4));
                float a = par ? acc[i][j].y : acc[i][j].x;
                l[j] = (n < N_) ? (a + bb[j]) : -1e30f;
            }
            float mx = l[0];
            #pragma unroll
            for (int j = 1; j < 8; ++j) mx = fmaxf(mx, l[j]);
            #pragma unroll
            for (int off = 1; off < 32; off <<= 1) mx = fmaxf(mx, __shfl_xor(mx, off, 64));
            float se = 0.f;
            #pragma unroll
            for (int j = 0; j < 8; ++j) se += expf(l[j] - mx);
            #pragma unroll
            for (int off = 1; off < 32; off <<= 1) se += __shfl_xor(se, off, 64);
            float lc = l[jq];
            float lm = __shfl(lc, (lane & 32) + cq, 64);
            if (cg == 0) col[t0 + tg * 16 + 2 * i + par] = expf(lm - mx) / se;
        }
    }
}

// ---------------- kernel 5: exact stable top-k by rank counting ----------------
__global__ void ktopk(const float* __restrict__ col, int* __restrict__ topk) {
    int ichunk = blockIdx.x;
    int b      = blockIdx.y;
    __shared__ float v[S_];
    #pragma unroll
    for (int r = 0; r < 8; ++r)
        v[threadIdx.x + r * 256] = col[(size_t)b * S_ + threadIdx.x + r * 256];
    __syncthreads();
    int i = ichunk * 256 + threadIdx.x;
    float vi = v[i];
    int cnt = 0;
    const float4* v4 = (const float4*)v;
    for (int j4 = 0; j4 < S_ / 4; ++j4) {
        float4 q = v4[j4];
        int j = j4 * 4;
        cnt += (q.x > vi) || (q.x == vi && (j + 0) < i);
        cnt += (q.y > vi) || (q.y == vi && (j + 1) < i);
        cnt += (q.z > vi) || (q.z == vi && (j + 2) < i);
        cnt += (q.w > vi) || (q.w == vi && (j + 3) < i);
    }
    if (cnt < KSEL) topk[b * KSEL + cnt] = i;
}

// ---------------- kernel 6: gather selected rows ----------------
__global__ void kgather(const float* __restrict__ x, const int* __restrict__ topk,
                        float* __restrict__ out) {
    int k = blockIdx.x;
    int b = blockIdx.y;
    int t = topk[b * KSEL + k];
    const float4* src = (const float4*)(x + (size_t)(b * S_ + t) * C_);
    float4*       dst = (float4*)(out + (size_t)(b * KSEL + k) * C_);
    dst[threadIdx.x] = src[threadIdx.x];
}

extern "C" void kernel_launch(void* const* d_in, const int* in_sizes, int n_in,
                              void* d_out, int out_size, void* d_ws, size_t ws_size,
                              hipStream_t stream) {
    const float* x    = (const float*)d_in[0];   // [32,2048,1536]
    const float* W    = (const float*)d_in[1];   // [200,1536]
    const float* bias = (const float*)d_in[2];   // [200]
    float* out = (float*)d_out;                  // [32,128,1536]

    float* part = (float*)d_ws;                  // 32*16*1536
    float* sumx = part + 32 * 16 * C_;           // 32*1536
    float* col  = sumx + 32 * C_;                // 65536
    int*   mids = (int*)(col + B_ * S_);         // 32
    int*   topk = mids + 32;                     // 32*128

    ksum_part<<<dim3(6, 16, 32), 256, 0, stream>>>(x, part);
    ksum_reduce<<<dim3(6, 32), 256, 0, stream>>>(part, sumx);
    kscore_argmax<<<32, 256, 0, stream>>>(sumx, W, bias, mids);
    kgemm_col<<<(B_ * S_) / TM, 256, 0, stream>>>(x, W, bias, mids, col);
    ktopk<<<dim3(8, 32), 256, 0, stream>>>(col, topk);
    kgather<<<dim3(KSEL, 32), 384, 0, stream>>>(x, topk, out);
}